// Round 2
// baseline (498.451 us; speedup 1.0000x reference)
//
#include <hip/hip_runtime.h>

#define B_DIM   512
#define IN_DIM  65536
#define OUT_DIM 16384
#define K_DIM   32

typedef float nfloat4 __attribute__((ext_vector_type(4)));   // native vec for nontemporal builtin

static __device__ __forceinline__ unsigned short f2bf(float f) {
    unsigned u = __builtin_bit_cast(unsigned, f);
    unsigned r = (u + 0x7FFFu + ((u >> 16) & 1u)) >> 16;   // round-to-nearest-even
    return (unsigned short)r;
}

static __device__ __forceinline__ float fcomp(float4 v, int c) {
    switch (c & 3) { case 0: return v.x; case 1: return v.y; case 2: return v.z; default: return v.w; }
}

// ---------------------------------------------------------------------------
// Kernel 1: transpose + fp32->bf16, NO LDS.
// Block = 512 threads, tile = 32 in-cols x all 512 b.
// Each thread owns one b-row and reads a FULL 128-B line (8x float4 from the
// same line -> 1 miss + 7 L1 hits; every line of x is read exactly once
// chip-wide -> FETCH == 128 MiB, no half-line amplification across XCDs).
// Writes: for fixed c, consecutive lanes = consecutive b -> 128 B/wave-instr;
// each block writes 32 complete 1-KiB xT rows -> full-line L2 writes.
// ---------------------------------------------------------------------------
__global__ __launch_bounds__(512) void transpose_bf16_k(const float* __restrict__ x,
                                                        unsigned short* __restrict__ xT) {
    const int c0 = blockIdx.x * 32;
    const int b  = threadIdx.x;
    const float4* p = (const float4*)(x + (size_t)b * IN_DIM + c0);
    float4 v[8];
    #pragma unroll
    for (int j = 0; j < 8; ++j) v[j] = p[j];
    #pragma unroll
    for (int c = 0; c < 32; ++c) {
        xT[(size_t)(c0 + c) * B_DIM + b] = f2bf(fcomp(v[c >> 2], c));
    }
}

// ---------------------------------------------------------------------------
// Kernel 2: main. Block = 256 threads (4 waves), owns 8 outputs x all 512 b.
// Each WAVE owns 2 outputs; each LANE owns 8 b's (16 B of a bf16 row), so one
// row-gather = ONE global_load_dwordx4 per wave (1 KiB payload/instr, half the
// load instructions of the uint2 version). 2048 blocks x 4 waves = 8192 waves
// = 32 waves/CU at VGPR<=64 (acc is only 16 VGPRs) -> ~2x in-flight misses to
// cover the L2-miss/L3-hit latency that bounded the previous version.
// idx/w tile preloaded one scalar per lane, broadcast via readlane -> uniform
// row base in SGPRs, voffset = lane*16 shared across all 64 gathers.
// Epilogue corner-turns through LDS for o-contiguous float4 out writes
// (nontemporal: out is write-once, keep it from evicting gather lines in L2).
// ---------------------------------------------------------------------------
#define SE 520   // epilogue LDS stride

__global__ __launch_bounds__(256, 8) void sparse_main(const unsigned short* __restrict__ xT,
                                                      const int*   __restrict__ idxp,
                                                      const float* __restrict__ wp,
                                                      const float* __restrict__ biasp,
                                                      float*       __restrict__ out) {
    __shared__ float lds[8][SE];
    const int o_blk = blockIdx.x * 8;
    const int t    = threadIdx.x;
    const int wid  = t >> 6;
    const int lane = t & 63;
    const int b8   = lane * 8;       // this thread's 8 b's

    // wave's idx/w tile: 2 o's x 32 k = 64 scalars = one per lane
    const int   iv = idxp[o_blk * K_DIM + wid * 64 + lane];
    const float wv = wp  [o_blk * K_DIM + wid * 64 + lane];

    float4 a0[2], a1[2];
    #pragma unroll
    for (int oo = 0; oo < 2; ++oo) {
        a0[oo] = make_float4(0.f, 0.f, 0.f, 0.f);
        a1[oo] = make_float4(0.f, 0.f, 0.f, 0.f);
    }

    #pragma unroll
    for (int oo = 0; oo < 2; ++oo) {
        #pragma unroll
        for (int k = 0; k < K_DIM; ++k) {
            const int L = oo * 32 + k;          // lane holding (oo,k)'s idx/w
            const int   sidx = __builtin_amdgcn_readlane(iv, L);
            const float sw   = __int_as_float(
                __builtin_amdgcn_readlane(__float_as_int(wv), L));
            const uint4 u = *(const uint4*)(xT + ((size_t)sidx << 9) + b8);
            a0[oo].x = fmaf(sw, __int_as_float(u.x << 16),          a0[oo].x);
            a0[oo].y = fmaf(sw, __int_as_float(u.x & 0xFFFF0000u),  a0[oo].y);
            a0[oo].z = fmaf(sw, __int_as_float(u.y << 16),          a0[oo].z);
            a0[oo].w = fmaf(sw, __int_as_float(u.y & 0xFFFF0000u),  a0[oo].w);
            a1[oo].x = fmaf(sw, __int_as_float(u.z << 16),          a1[oo].x);
            a1[oo].y = fmaf(sw, __int_as_float(u.z & 0xFFFF0000u),  a1[oo].y);
            a1[oo].z = fmaf(sw, __int_as_float(u.w << 16),          a1[oo].z);
            a1[oo].w = fmaf(sw, __int_as_float(u.w & 0xFFFF0000u),  a1[oo].w);
        }
    }

    #pragma unroll
    for (int oo = 0; oo < 2; ++oo) {
        const float bv = biasp[o_blk + wid * 2 + oo];
        a0[oo].x += bv; a0[oo].y += bv; a0[oo].z += bv; a0[oo].w += bv;
        a1[oo].x += bv; a1[oo].y += bv; a1[oo].z += bv; a1[oo].w += bv;
        *(float4*)(&lds[wid * 2 + oo][b8])     = a0[oo];
        *(float4*)(&lds[wid * 2 + oo][b8 + 4]) = a1[oo];
    }
    __syncthreads();

    // corner-turn write: 512 b x 8 o = 4096 floats, 4 passes of 1024
    #pragma unroll
    for (int p = 0; p < 4; ++p) {
        const int q = p * 1024 + t * 4;
        const int b = q >> 3;
        const int o = q & 7;            // 0 or 4
        nfloat4 v;
        v.x = lds[o + 0][b];
        v.y = lds[o + 1][b];
        v.z = lds[o + 2][b];
        v.w = lds[o + 3][b];
        __builtin_nontemporal_store(v, (nfloat4*)(out + (size_t)b * OUT_DIM + o_blk + o));
    }
}

// ---------------------------------------------------------------------------
// Fallback (workspace too small): direct gather, correct but slow.
// ---------------------------------------------------------------------------
__global__ void sparse_fallback(const float* __restrict__ x,
                                const int*   __restrict__ idxp,
                                const float* __restrict__ wp,
                                const float* __restrict__ biasp,
                                float*       __restrict__ out) {
    const int i = blockIdx.x * blockDim.x + threadIdx.x;
    if (i >= B_DIM * OUT_DIM) return;
    const int b = i / OUT_DIM;
    const int o = i % OUT_DIM;
    float a = biasp[o];
    for (int k = 0; k < K_DIM; ++k) {
        const int idx = idxp[o * K_DIM + k];
        a = fmaf(wp[o * K_DIM + k], x[(size_t)b * IN_DIM + idx], a);
    }
    out[i] = a;
}

extern "C" void kernel_launch(void* const* d_in, const int* in_sizes, int n_in,
                              void* d_out, int out_size, void* d_ws, size_t ws_size,
                              hipStream_t stream) {
    const float* x       = (const float*)d_in[0];
    const int*   indices = (const int*)  d_in[1];
    const float* weight  = (const float*)d_in[2];
    const float* bias    = (const float*)d_in[3];
    float*       out     = (float*)d_out;

    const size_t need = (size_t)IN_DIM * B_DIM * sizeof(unsigned short);  // 64 MiB
    if (ws_size >= need) {
        unsigned short* xT = (unsigned short*)d_ws;
        transpose_bf16_k<<<IN_DIM / 32, 512, 0, stream>>>(x, xT);
        sparse_main<<<OUT_DIM / 8, 256, 0, stream>>>(xT, indices, weight, bias, out);
    } else {
        const int n = B_DIM * OUT_DIM;
        sparse_fallback<<<(n + 255) / 256, 256, 0, stream>>>(x, indices, weight, bias, out);
    }
}